// Round 8
// baseline (165.793 us; speedup 1.0000x reference)
//
#include <hip/hip_runtime.h>
#include <math.h>

// ---------------------------------------------------------------------------
// VMD, T = 2^20, K = 3.  u[k][t] = (f_hat[t] - lam[t]/2) * g_k(t), g_k real.
// fftshift folded into (-1)^n input modulation; ifftshift into (-1)^n output.
//
// Round-19: round-18 (float4 IO + rev-trig) was null -> FFT side not bound
// by IO requests or trig.  Bank arithmetic on the Stockham LDS pattern:
// float2 writes dst[base+k*Ns] at Ns=1 hit banks {0,8,16,24} (16 lanes/bank
// = 4x the b64 minimum), Ns=4 hits {0,2,4,6} (4x) -> ~2/5 of all LDS
// traffic pays ~4x, on the barrier-separated critical path of every FFT
// stage.  Fix: pad index PADI(i)=i+(i>>4); all stages then hit the 4/bank
// minimum (verified per-stage by hand).  Addresses only; arithmetic
// bit-identical.  k_omega parked (~56.6us latency chain, rounds 12-17).
// ---------------------------------------------------------------------------

#define TN        (1 << 20)
#define NBINS     1024
#define PPB       1024         // points per bin (TN/NBINS)
#define FALPHA    2000.0f
#define FTAU      1e-7f
#define FTOL      1e-6f
#define FEPS      1e-8f
#define FTWO_PI   6.28318530717958647692f
#define FINV_T    (1.0f / 1048576.0f)

#define PADI(i)   ((i) + ((i) >> 4))   // LDS anti-conflict pad (float2 elems)
#define PBUF      1088                 // >= PADI(1023)+1 = 1087

__device__ __forceinline__ float2 cmulf(float2 a, float2 b) {
    return make_float2(a.x * b.x - a.y * b.y, a.x * b.y + a.y * b.x);
}
// cis in REVOLUTIONS: returns (cos(2*pi*r), sgn*sin(2*pi*r)); r in [0,1).
__device__ __forceinline__ float2 cis_rev(float r, float sgn) {
    return make_float2(__builtin_amdgcn_cosf(r),
                       sgn * __builtin_amdgcn_sinf(r));
}
__device__ __forceinline__ float rlanef(float v, int l) {
    return __int_as_float(__builtin_amdgcn_readlane(__float_as_int(v), l));
}

// g_k(fr) for K=3 with neighbor coupling (stale omega, like the reference)
__device__ __forceinline__ void g3f(float fr, float om0, float om1, float om2,
                                    float& g0, float& g1, float& g2) {
    const float tau2 = FTAU * FTAU;
    float d0 = fr - om0; d0 *= d0;
    float d1 = fr - om1; d1 *= d1;
    float d2 = fr - om2; d2 *= d2;
    g0 = __builtin_amdgcn_rcpf(1.0f + FALPHA * (d0 + d1 + tau2));
    g1 = __builtin_amdgcn_rcpf(1.0f + FALPHA * (d0 + d1 + d2 + tau2));
    g2 = __builtin_amdgcn_rcpf(1.0f + FALPHA * (d1 + d2 + tau2));
}

// wave64 sum via DPP: result valid in lane 63.
__device__ __forceinline__ float dpp_wave_sum(float x) {
    x += __int_as_float(__builtin_amdgcn_update_dpp(
             0, __float_as_int(x), 0x111, 0xf, 0xf, true));  // row_shr:1
    x += __int_as_float(__builtin_amdgcn_update_dpp(
             0, __float_as_int(x), 0x112, 0xf, 0xf, true));  // row_shr:2
    x += __int_as_float(__builtin_amdgcn_update_dpp(
             0, __float_as_int(x), 0x114, 0xf, 0xf, true));  // row_shr:4
    x += __int_as_float(__builtin_amdgcn_update_dpp(
             0, __float_as_int(x), 0x118, 0xf, 0xf, true));  // row_shr:8
    x += __int_as_float(__builtin_amdgcn_update_dpp(
             0, __float_as_int(x), 0x142, 0xf, 0xf, true));  // row_bcast:15
    x += __int_as_float(__builtin_amdgcn_update_dpp(
             0, __float_as_int(x), 0x143, 0xf, 0xf, true));  // row_bcast:31
    return x;
}
// 32-lane sums: lane31 = sum(0..31), lane63 = sum(32..63).
__device__ __forceinline__ float dpp_sum32(float x) {
    x += __int_as_float(__builtin_amdgcn_update_dpp(
             0, __float_as_int(x), 0x111, 0xf, 0xf, true));
    x += __int_as_float(__builtin_amdgcn_update_dpp(
             0, __float_as_int(x), 0x112, 0xf, 0xf, true));
    x += __int_as_float(__builtin_amdgcn_update_dpp(
             0, __float_as_int(x), 0x114, 0xf, 0xf, true));
    x += __int_as_float(__builtin_amdgcn_update_dpp(
             0, __float_as_int(x), 0x118, 0xf, 0xf, true));
    x += __int_as_float(__builtin_amdgcn_update_dpp(
             0, __float_as_int(x), 0x142, 0xf, 0xf, true));  // row_bcast:15
    return x;
}

// ---------------------------------------------------------------------------
// fused |fhat|^2 + transpose + bin-partials (unchanged).
// ---------------------------------------------------------------------------
__global__ __launch_bounds__(256)
void k_binpart(const float2* __restrict__ in, float* __restrict__ pB,
               float* __restrict__ pM) {
    __shared__ float tile[32][33];
    const int bx = blockIdx.x * 32, by = blockIdx.y * 32;
    const int tx = threadIdx.x, ty = threadIdx.y;
#pragma unroll
    for (int j = 0; j < 32; j += 8) {
        const float2 v = in[(size_t)(by + ty + j) * 1024 + bx + tx];
        tile[ty + j][tx] = v.x * v.x + v.y * v.y;
    }
    __syncthreads();
    const int sIdx = blockIdx.y;              // slab (which 32-col group)
    const float d = ((float)(by + tx) - 511.5f) * FINV_T;  // fr - bin center
    const int lane = (tx + 32 * ty) & 63;
#pragma unroll
    for (int j = 0; j < 32; j += 8) {
        float s = tile[tx][ty + j];           // m2 at (r_true=bx+ty+j, c_true=by+tx)
        float m = s * d;
        s = dpp_sum32(s);
        m = dpp_sum32(m);
        if (lane == 31 || lane == 63) {
            const int bin = bx + ty + j;      // = r_true
            pB[bin * 32 + sIdx] = s;
            pM[bin * 32 + sIdx] = m;
        }
    }
}

// ---------------------------------------------------------------------------
// 49 omega updates over 1024 bins: 256 threads x 4 bins (4 waves, 1/SIMD).
// Parked: latency-chain floor ~56.6us (rounds 12-17 bracket it).
// ---------------------------------------------------------------------------
__global__ __launch_bounds__(256)
void k_omega(const float* __restrict__ pB, const float* __restrict__ pM,
             const float* __restrict__ omega0,
             float* __restrict__ oomf, float* __restrict__ sgsb) {
    const int tid = threadIdx.x;
    const int lane = tid & 63, wid = tid >> 6;   // 4 waves
    const float kA = -4.0f * FALPHA;

    float B[4], M[4], C[4], SG[4], gp[4];
    const float4* __restrict__ pB4 = (const float4*)pB;
    const float4* __restrict__ pM4 = (const float4*)pM;
#pragma unroll
    for (int i = 0; i < 4; ++i) {
        const int j = tid + 256 * i;
        float sb = 0.f, sm = 0.f;
#pragma unroll
        for (int s = 0; s < 8; ++s) {         // fixed order -> deterministic
            const float4 b = pB4[j * 8 + s];
            sb += b.x; sb += b.y; sb += b.z; sb += b.w;
            const float4 m = pM4[j * 8 + s];
            sm += m.x; sm += m.y; sm += m.z; sm += m.w;
        }
        B[i] = sb; M[i] = sm;
        C[i] = ((float)(j * PPB) + 511.5f) * FINV_T - 0.5f;
        SG[i] = 0.f; gp[i] = 0.f;
    }

    float om0 = 0.5f * omega0[0];
    float om1 = 0.5f * omega0[1];
    float om2 = 0.5f * omega0[2];
    float op0 = om0, op1 = om1, op2 = om2;
    float n0 = om0, n1 = om1, n2 = om2;
    float stop = 0.f;

    __shared__ float wsum[2][4][8];           // parity double-buffer
    bool fin = true;

    for (int n = 0; n < 49; ++n) {
        if (n > 0) {
            if (stop != 0.f) { fin = false; break; }
            op0 = om0; op1 = om1; op2 = om2;
            om0 = n0; om1 = n1; om2 = n2;
#pragma unroll
            for (int i = 0; i < 4; ++i) SG[i] += gp[i] - 1.0f;  // gs_{n-1}
        }
        const int check = (n > 0 && n % 10 == 0);

        float a[8];
#pragma unroll
        for (int v = 0; v < 8; ++v) a[v] = 0.f;

#pragma unroll
        for (int i = 0; i < 4; ++i) {
            const float c  = C[i];
            const float Bv = B[i];
            const float M1 = M[i];
            const float e0 = c - om0, e1 = c - om1, e2 = c - om2;
            float g0, g1, g2;
            g3f(c, om0, om1, om2, g0, g1, g2);
            const float gsq0 = g0 * g0, gsq1 = g1 * g1, gsq2 = g2 * g2;
            const float gc0 = gsq0 * g0, gc1 = gsq1 * g1, gc2 = gsq2 * g2;
            const float Dp0 = e0 + e1, Dp1 = e0 + e1 + e2, Dp2 = e1 + e2;
            const float P0 = gsq0 * Bv + kA * Dp0 * gc0 * M1;
            const float P1 = gsq1 * Bv + kA * Dp1 * gc1 * M1;
            const float P2 = gsq2 * Bv + kA * Dp2 * gc2 * M1;
            a[0] += P0; a[1] += P1; a[2] += P2;
            a[3] += c * P0 + gsq0 * M1;
            a[4] += c * P1 + gsq1 * M1;
            a[5] += c * P2 + gsq2 * M1;
            gp[i] = g0 + g1 + g2;
            if (check) {
                float h0, h1, h2;
                g3f(c, op0, op1, op2, h0, h1, h2);
                const float d0 = g0 - h0, d1 = g1 - h1, d2 = g2 - h2;
                a[6] += Bv * (d0 * d0 + d1 * d1 + d2 * d2);
                a[7] += Bv * (h0 * h0 + h1 * h1 + h2 * h2);
            }
        }
#pragma unroll
        for (int v = 0; v < 6; ++v) a[v] = dpp_wave_sum(a[v]);
        if (check) {
            a[6] = dpp_wave_sum(a[6]);
            a[7] = dpp_wave_sum(a[7]);
        }
        if (lane == 63) {
            *(float4*)&wsum[n & 1][wid][0] = make_float4(a[0], a[1], a[2], a[3]);
            *(float4*)&wsum[n & 1][wid][4] = make_float4(a[4], a[5], a[6], a[7]);
        }
        __syncthreads();                       // the ONLY barrier per iter
        float r = 0.f;
#pragma unroll
        for (int w = 0; w < 4; ++w) r += wsum[n & 1][w][lane & 7];
        const float S0 = rlanef(r, 0), S1 = rlanef(r, 1), S2 = rlanef(r, 2);
        const float S3 = rlanef(r, 3), S4 = rlanef(r, 4), S5 = rlanef(r, 5);
        n0 = S3 * __builtin_amdgcn_rcpf(S0 + FEPS);
        n1 = S4 * __builtin_amdgcn_rcpf(S1 + FEPS);
        n2 = S5 * __builtin_amdgcn_rcpf(S2 + FEPS);
        if (check) {
            const float S6 = rlanef(r, 6), S7 = rlanef(r, 7);
            const float ud = S6 * __builtin_amdgcn_rcpf(S7 + FEPS);
            const float od = (fabsf(n0 - n2) + fabsf(n1 - n0) +
                              fabsf(n2 - n1)) * (1.0f / 3.0f);
            stop = (ud < FTOL && od < FTOL) ? 1.f : 0.f;
        }
    }

    if (fin) {             // completed: omega entering iter 49, sgs 0..48
#pragma unroll
        for (int i = 0; i < 4; ++i) SG[i] += gp[i] - 1.0f;
        om0 = n0; om1 = n1; om2 = n2;
    }
#pragma unroll
    for (int i = 0; i < 4; ++i) sgsb[tid + 256 * i] = SG[i];
    if (tid == 0) { oomf[0] = om0; oomf[1] = om1; oomf[2] = om2; }
}

// ---------------------------------------------------------------------------
// 1024-point Stockham radix-4 stages in LDS, PADDED indexing (PADI).
// Caller fills bufA at PADI(i), then syncs.  Returns buffer with result at
// PADI(i).  Arithmetic identical to unpadded version.
// ---------------------------------------------------------------------------
__device__ __forceinline__ float2* fft1024_stages(float2* bufA, float2* bufB,
                                                  int t, float dir) {
    float2* src = bufA;
    float2* dst = bufB;
    int Ns = 1;
#pragma unroll
    for (int s = 0; s < 5; ++s) {
        const int jm = t & (Ns - 1);
        float2 v0 = src[PADI(t)],       v1 = src[PADI(t + 256)];
        float2 v2 = src[PADI(t + 512)], v3 = src[PADI(t + 768)];
        const float rv = (float)jm * (0.25f / (float)Ns);
        float2 w1 = cis_rev(rv, dir);
        float2 w2 = cmulf(w1, w1);
        float2 w3 = cmulf(w2, w1);
        v1 = cmulf(v1, w1); v2 = cmulf(v2, w2); v3 = cmulf(v3, w3);
        float2 s0 = make_float2(v0.x + v2.x, v0.y + v2.y);
        float2 s1 = make_float2(v0.x - v2.x, v0.y - v2.y);
        float2 s2 = make_float2(v1.x + v3.x, v1.y + v3.y);
        float2 s3 = make_float2(v1.x - v3.x, v1.y - v3.y);
        float2 s3i = make_float2(-dir * s3.y, dir * s3.x);  // dir*i * s3
        const int base = ((t - jm) << 2) + jm;
        dst[PADI(base)]          = make_float2(s0.x + s2.x, s0.y + s2.y);
        dst[PADI(base + Ns)]     = make_float2(s1.x + s3i.x, s1.y + s3i.y);
        dst[PADI(base + 2 * Ns)] = make_float2(s0.x - s2.x, s0.y - s2.y);
        dst[PADI(base + 3 * Ns)] = make_float2(s1.x - s3i.x, s1.y - s3i.y);
        __syncthreads();
        float2* tmp = src; src = dst; dst = tmp;
        Ns <<= 2;
    }
    return src;
}

// 4-column slab version: buffers [4][PBUF]; per-stage twiddles shared.
__device__ __forceinline__ float2* fft1024_stages4(float2* bufA, float2* bufB,
                                                   int t, float dir) {
    float2* src = bufA;
    float2* dst = bufB;
    int Ns = 1;
#pragma unroll
    for (int s = 0; s < 5; ++s) {
        const int jm = t & (Ns - 1);
        const float rv = (float)jm * (0.25f / (float)Ns);
        float2 w1 = cis_rev(rv, dir);
        float2 w2 = cmulf(w1, w1);
        float2 w3 = cmulf(w2, w1);
        const int base = ((t - jm) << 2) + jm;
#pragma unroll
        for (int q = 0; q < 4; ++q) {
            const int o = q * PBUF;
            float2 v0 = src[o + PADI(t)],       v1 = src[o + PADI(t + 256)];
            float2 v2 = src[o + PADI(t + 512)], v3 = src[o + PADI(t + 768)];
            v1 = cmulf(v1, w1); v2 = cmulf(v2, w2); v3 = cmulf(v3, w3);
            float2 s0 = make_float2(v0.x + v2.x, v0.y + v2.y);
            float2 s1 = make_float2(v0.x - v2.x, v0.y - v2.y);
            float2 s2 = make_float2(v1.x + v3.x, v1.y + v3.y);
            float2 s3 = make_float2(v1.x - v3.x, v1.y - v3.y);
            float2 s3i = make_float2(-dir * s3.y, dir * s3.x);
            dst[o + PADI(base)]          = make_float2(s0.x + s2.x, s0.y + s2.y);
            dst[o + PADI(base + Ns)]     = make_float2(s1.x + s3i.x, s1.y + s3i.y);
            dst[o + PADI(base + 2 * Ns)] = make_float2(s0.x - s2.x, s0.y - s2.y);
            dst[o + PADI(base + 3 * Ns)] = make_float2(s1.x - s3i.x, s1.y - s3i.y);
        }
        __syncthreads();
        float2* tmp = src; src = dst; dst = tmp;
        Ns <<= 2;
    }
    return src;
}

// generic row FFT (no output twiddle; forward second stage).
__global__ __launch_bounds__(256)
void k_fft1024(const float2* __restrict__ in, float2* __restrict__ out,
               float dir) {
    __shared__ float2 bufA[PBUF];
    __shared__ float2 bufB[PBUF];
    const int row  = blockIdx.x;
    const float2* __restrict__ rin  = in  + (size_t)row * 1024;
    float2* __restrict__ rout = out + (size_t)row * 1024;
    const int t = threadIdx.x;
#pragma unroll
    for (int r = 0; r < 4; ++r) {
        const int c = t + 256 * r;
        bufA[PADI(c)] = rin[c];
    }
    __syncthreads();
    float2* src = fft1024_stages(bufA, bufB, t, dir);
#pragma unroll
    for (int r = 0; r < 4; ++r) {
        const int c = t + 256 * r;
        rout[c] = src[PADI(c)];
    }
}

// ---------------------------------------------------------------------------
// forward slab: replaces tr_fwd_in + fft1024(tw) + tr_c2c (3 passes -> 1).
// ---------------------------------------------------------------------------
__global__ __launch_bounds__(256)
void k_fftfwd_slab(const float* __restrict__ x, float2* __restrict__ sA) {
    __shared__ float2 bufA[4][PBUF];
    __shared__ float2 bufB[4][PBUF];
    const int a0 = blockIdx.x * 4;
    const int t  = threadIdx.x;
#pragma unroll
    for (int r = 0; r < 4; ++r) {
        const int p = t + 256 * r;
        const float4 v = *(const float4*)(x + (size_t)p * 1024 + a0);
        const int pi = PADI(p);
        bufA[0][pi] = make_float2( v.x, 0.f);
        bufA[1][pi] = make_float2(-v.y, 0.f);
        bufA[2][pi] = make_float2( v.z, 0.f);
        bufA[3][pi] = make_float2(-v.w, 0.f);
    }
    __syncthreads();
    float2* src = fft1024_stages4(&bufA[0][0], &bufB[0][0], t, -1.0f);
#pragma unroll
    for (int r = 0; r < 4; ++r) {
        const int c = t + 256 * r;
        const int ci = PADI(c);
        float2 o[4];
#pragma unroll
        for (int q = 0; q < 4; ++q) {
            const unsigned p = ((unsigned)(a0 + q) * (unsigned)c) & 1048575u;
            o[q] = cmulf(src[q * PBUF + ci], cis_rev((float)p * FINV_T, -1.0f));
        }
        float2* w = sA + (size_t)c * 1024 + a0;
        *(float4*)(w)     = make_float4(o[0].x, o[0].y, o[1].x, o[1].y);
        *(float4*)(w + 2) = make_float4(o[2].x, o[2].y, o[3].x, o[3].y);
    }
}

// ---------------------------------------------------------------------------
// inverse slab: replaces tr_c2c + fft1024(inv) + tr_out (3 passes -> 1).
// ---------------------------------------------------------------------------
__global__ __launch_bounds__(256)
void k_ifft_slab(const float2* __restrict__ zin, float* __restrict__ out,
                 int zbase) {
    __shared__ float2 bufA[4][PBUF];
    __shared__ float2 bufB[4][PBUF];
    const int m0 = blockIdx.x * 4;
    const int zi = blockIdx.y;
    const int z  = zi + zbase;
    const int t  = threadIdx.x;
    const float2* __restrict__ Z = zin + (size_t)zi * TN;
#pragma unroll
    for (int r = 0; r < 4; ++r) {
        const int k = t + 256 * r;
        const float4 u0 = *(const float4*)(Z + (size_t)k * 1024 + m0);
        const float4 u1 = *(const float4*)(Z + (size_t)k * 1024 + m0 + 2);
        const int ki = PADI(k);
        bufA[0][ki] = make_float2(u0.x, u0.y);
        bufA[1][ki] = make_float2(u0.z, u0.w);
        bufA[2][ki] = make_float2(u1.x, u1.y);
        bufA[3][ki] = make_float2(u1.z, u1.w);
    }
    __syncthreads();
    float2* src = fft1024_stages4(&bufA[0][0], &bufB[0][0], t, 1.0f);
#pragma unroll
    for (int r = 0; r < 4; ++r) {
        const int m2 = t + 256 * r;
        const int mi = PADI(m2);
        float re[4], im[4];
#pragma unroll
        for (int q = 0; q < 4; ++q) {
            const float sgn = (q & 1) ? -FINV_T : FINV_T;   // (-1)^{m0+q}, m0 even
            const float2 v = src[q * PBUF + mi];
            re[q] = v.x * sgn;
            im[q] = v.y * sgn;
        }
        const size_t idx = (size_t)m2 * 1024 + m0;
        if (z == 0) {
            *(float4*)(out + idx) =
                make_float4(re[0], re[1], re[2], re[3]);            // imf0
            *(float4*)(out + (size_t)TN + idx) =
                make_float4(im[0], im[1], im[2], im[3]);            // imf1
        } else {
            *(float4*)(out + 2 * (size_t)TN + idx) =
                make_float4(re[0], re[1], re[2], re[3]);            // imf2
        }
    }
}

// single-z filter + row-iFFT (non-batch2 workspace path).
__global__ __launch_bounds__(256)
void k_fftu(const float2* __restrict__ fhat, const float* __restrict__ sgsb,
            const float* __restrict__ oomf,
            float2* __restrict__ out, int zbase) {
    __shared__ float2 bufA[PBUF];
    __shared__ float2 bufB[PBUF];
    const int row = blockIdx.x & 1023;
    const int zi  = blockIdx.x >> 10;
    const int z   = zi + zbase;
    const float om0 = oomf[0], om1 = oomf[1], om2 = oomf[2];
    const float2* __restrict__ frow = fhat + (size_t)row * 1024;
    const int t = threadIdx.x;
#pragma unroll
    for (int r = 0; r < 4; ++r) {
        const int c = t + 256 * r;
        const float2 f = frow[c];
        const int tt = (c << 10) | row;
        const float fr = (float)tt * FINV_T - 0.5f;
        const float sc = 1.0f - 0.5f * FTAU * sgsb[tt >> 10];
        float g0, g1, g2;
        g3f(fr, om0, om1, om2, g0, g1, g2);
        const int tm = (TN - tt) & (TN - 1);
        const float frm = (float)tm * FINV_T - 0.5f;
        const float scm = 1.0f - 0.5f * FTAU * sgsb[tm >> 10];
        float h0, h1, h2;
        g3f(frm, om0, om1, om2, h0, h1, h2);
        float A, Bi;
        if (z == 0) {
            A  = 0.5f * (g0 * sc + h0 * scm);
            Bi = 0.5f * (g1 * sc + h1 * scm);
        } else {
            A  = 0.5f * (g2 * sc + h2 * scm);
            Bi = 0.f;
        }
        bufA[PADI(c)] = cmulf(f, make_float2(A, Bi));
    }
    __syncthreads();
    float2* src = fft1024_stages(bufA, bufB, t, 1.0f);
    float2* __restrict__ rout = out + (size_t)zi * TN + (size_t)row * 1024;
#pragma unroll
    for (int r = 0; r < 4; ++r) {
        const int c = t + 256 * r;
        const unsigned p = ((unsigned)row * (unsigned)c) & 1048575u;
        rout[c] = cmulf(src[PADI(c)], cis_rev((float)p * FINV_T, 1.0f));
    }
}

// fused both-z variant (batch2 path): one fhat load, one g3f set -> both
// filter products; two back-to-back 1024-pt iFFTs; output twiddles reused.
__global__ __launch_bounds__(256)
void k_fftu2(const float2* __restrict__ fhat, const float* __restrict__ sgsb,
             const float* __restrict__ oomf, float2* __restrict__ out) {
    __shared__ float2 bufA[PBUF];
    __shared__ float2 bufB[PBUF];
    const int row = blockIdx.x;
    const float om0 = oomf[0], om1 = oomf[1], om2 = oomf[2];
    const float2* __restrict__ frow = fhat + (size_t)row * 1024;
    const int t = threadIdx.x;
    float2 fsave[4];
    float  A2s[4];
    float2 tws[4];
#pragma unroll
    for (int r = 0; r < 4; ++r) {
        const int c = t + 256 * r;
        const float2 f = frow[c];
        const int tt = (c << 10) | row;
        const float fr = (float)tt * FINV_T - 0.5f;
        const float sc = 1.0f - 0.5f * FTAU * sgsb[tt >> 10];
        float g0, g1, g2;
        g3f(fr, om0, om1, om2, g0, g1, g2);
        const int tm = (TN - tt) & (TN - 1);
        const float frm = (float)tm * FINV_T - 0.5f;
        const float scm = 1.0f - 0.5f * FTAU * sgsb[tm >> 10];
        float h0, h1, h2;
        g3f(frm, om0, om1, om2, h0, h1, h2);
        const float A  = 0.5f * (g0 * sc + h0 * scm);
        const float Bi = 0.5f * (g1 * sc + h1 * scm);
        A2s[r]   = 0.5f * (g2 * sc + h2 * scm);
        fsave[r] = f;
        bufA[PADI(c)] = cmulf(f, make_float2(A, Bi));
    }
    __syncthreads();
    float2* src = fft1024_stages(bufA, bufB, t, 1.0f);   // = bufB
    float2* __restrict__ r0 = out + (size_t)row * 1024;
#pragma unroll
    for (int r = 0; r < 4; ++r) {
        const int c = t + 256 * r;
        const unsigned p = ((unsigned)row * (unsigned)c) & 1048575u;
        tws[r] = cis_rev((float)p * FINV_T, 1.0f);
        r0[c] = cmulf(src[PADI(c)], tws[r]);
    }
    // refill bufA for z=1 (safe: stage 4 read bufA before its barrier);
    // barrier below also fences the r0 reads of bufB before stage 0 writes.
#pragma unroll
    for (int r = 0; r < 4; ++r) {
        const int c = t + 256 * r;
        bufA[PADI(c)] = cmulf(fsave[r], make_float2(A2s[r], 0.f));
    }
    __syncthreads();
    src = fft1024_stages(bufA, bufB, t, 1.0f);
    float2* __restrict__ r1 = out + (size_t)TN + (size_t)row * 1024;
#pragma unroll
    for (int r = 0; r < 4; ++r) {
        const int c = t + 256 * r;
        r1[c] = cmulf(src[PADI(c)], tws[r]);
    }
}

// ---------------------------------------------------------------------------
extern "C" void kernel_launch(void* const* d_in, const int* in_sizes, int n_in,
                              void* d_out, int out_size, void* d_ws, size_t ws_size,
                              hipStream_t stream) {
    (void)in_sizes; (void)n_in; (void)out_size;
    const float* x      = (const float*)d_in[0];
    const float* omega0 = (const float*)d_in[1];
    float* outp = (float*)d_out;
    char* ws = (char*)d_ws;

    const size_t MB = (size_t)1 << 20;
    const size_t KB = (size_t)1 << 10;
    float2* fhat = (float2*)(ws);                      // 8 MB (scrambled)
    float*  pB   = (float*)(ws + 8 * MB);              // 128 KB
    float*  pM   = (float*)(ws + 8 * MB + 128 * KB);   // 128 KB
    float*  sgsb = (float*)(ws + 8 * MB + 256 * KB);   // 4 KB
    float*  oomf = (float*)(ws + 8 * MB + 264 * KB);   // 3 floats
    const bool batch2 = ws_size >= 42 * MB;
    float2* sA = (float2*)(ws + 9 * MB);               // 8 MB
    float2* sB = batch2 ? (float2*)(ws + 25 * MB)      // 16 MB (both z)
                        : (float2*)(ws + 17 * MB);     // 8 MB (one z)

    // forward: slab col-FFT (+twiddle, transposed write) then row FFT
    k_fftfwd_slab<<<256, 256, 0, stream>>>(x, sA);
    k_fft1024<<<1024, 256, 0, stream>>>(sA, fhat, -1.0f);

    // fused spectrum compression: fhat -> per-slab bin partials
    k_binpart<<<dim3(32, 32), dim3(32, 8), 0, stream>>>(fhat, pB, pM);

    // 49 omega updates in one small block
    k_omega<<<1, 256, 0, stream>>>(pB, pM, omega0, oomf, sgsb);

    // Hermitian-packed inverse: filter+row-iFFT, then slab col-iFFT that
    // writes the 3 real IMFs directly in natural order.
    if (batch2) {
        k_fftu2<<<1024, 256, 0, stream>>>(fhat, sgsb, oomf, sB);
        k_ifft_slab<<<dim3(256, 2), 256, 0, stream>>>(sB, outp, 0);
    } else {
        for (int z = 0; z < 2; ++z) {
            k_fftu<<<1024, 256, 0, stream>>>(fhat, sgsb, oomf, sB, z);
            k_ifft_slab<<<dim3(256, 1), 256, 0, stream>>>(sB, outp, z);
        }
    }
}

// Round 9
// 164.768 us; speedup vs baseline: 1.0062x; 1.0062x over previous
//
#include <hip/hip_runtime.h>
#include <math.h>

// ---------------------------------------------------------------------------
// VMD, T = 2^20, K = 3.  u[k][t] = (f_hat[t] - lam[t]/2) * g_k(t), g_k real.
// fftshift folded into (-1)^n input modulation; ifftshift into (-1)^n output.
//
// Round-20: rounds 18/19 nulls ruled out IO-requests, trig, LDS banks.  The
// slab kernels run at 1 wave/SIMD (68KB LDS, 256 thr, grid<=2 blk/CU) --
// the exact config that cost k_omega 2.15x in round-14 -- and k_fftu2 runs
// its two iFFTs serially.  Fix: 512-thread slab kernels (2 cols per
// half-block -> 2 butterflies/thread/stage, 2 waves/SIMD) and a 512-thread
// fftu2 running both z-FFTs CONCURRENTLY in separate LDS buffers.
// Arithmetic bit-identical; only thread->work assignment changes.
// k_omega parked (~57us latency chain, rounds 12-17 bracket).
// ---------------------------------------------------------------------------

#define TN        (1 << 20)
#define NBINS     1024
#define PPB       1024         // points per bin (TN/NBINS)
#define FALPHA    2000.0f
#define FTAU      1e-7f
#define FTOL      1e-6f
#define FEPS      1e-8f
#define FTWO_PI   6.28318530717958647692f
#define FINV_T    (1.0f / 1048576.0f)

#define PADI(i)   ((i) + ((i) >> 4))   // LDS anti-conflict pad (float2 elems)
#define PBUF      1088                 // >= PADI(1023)+1 = 1087

__device__ __forceinline__ float2 cmulf(float2 a, float2 b) {
    return make_float2(a.x * b.x - a.y * b.y, a.x * b.y + a.y * b.x);
}
// cis in REVOLUTIONS: returns (cos(2*pi*r), sgn*sin(2*pi*r)); r in [0,1).
__device__ __forceinline__ float2 cis_rev(float r, float sgn) {
    return make_float2(__builtin_amdgcn_cosf(r),
                       sgn * __builtin_amdgcn_sinf(r));
}
__device__ __forceinline__ float rlanef(float v, int l) {
    return __int_as_float(__builtin_amdgcn_readlane(__float_as_int(v), l));
}

// g_k(fr) for K=3 with neighbor coupling (stale omega, like the reference)
__device__ __forceinline__ void g3f(float fr, float om0, float om1, float om2,
                                    float& g0, float& g1, float& g2) {
    const float tau2 = FTAU * FTAU;
    float d0 = fr - om0; d0 *= d0;
    float d1 = fr - om1; d1 *= d1;
    float d2 = fr - om2; d2 *= d2;
    g0 = __builtin_amdgcn_rcpf(1.0f + FALPHA * (d0 + d1 + tau2));
    g1 = __builtin_amdgcn_rcpf(1.0f + FALPHA * (d0 + d1 + d2 + tau2));
    g2 = __builtin_amdgcn_rcpf(1.0f + FALPHA * (d1 + d2 + tau2));
}

// wave64 sum via DPP: result valid in lane 63.
__device__ __forceinline__ float dpp_wave_sum(float x) {
    x += __int_as_float(__builtin_amdgcn_update_dpp(
             0, __float_as_int(x), 0x111, 0xf, 0xf, true));  // row_shr:1
    x += __int_as_float(__builtin_amdgcn_update_dpp(
             0, __float_as_int(x), 0x112, 0xf, 0xf, true));  // row_shr:2
    x += __int_as_float(__builtin_amdgcn_update_dpp(
             0, __float_as_int(x), 0x114, 0xf, 0xf, true));  // row_shr:4
    x += __int_as_float(__builtin_amdgcn_update_dpp(
             0, __float_as_int(x), 0x118, 0xf, 0xf, true));  // row_shr:8
    x += __int_as_float(__builtin_amdgcn_update_dpp(
             0, __float_as_int(x), 0x142, 0xf, 0xf, true));  // row_bcast:15
    x += __int_as_float(__builtin_amdgcn_update_dpp(
             0, __float_as_int(x), 0x143, 0xf, 0xf, true));  // row_bcast:31
    return x;
}
// 32-lane sums: lane31 = sum(0..31), lane63 = sum(32..63).
__device__ __forceinline__ float dpp_sum32(float x) {
    x += __int_as_float(__builtin_amdgcn_update_dpp(
             0, __float_as_int(x), 0x111, 0xf, 0xf, true));
    x += __int_as_float(__builtin_amdgcn_update_dpp(
             0, __float_as_int(x), 0x112, 0xf, 0xf, true));
    x += __int_as_float(__builtin_amdgcn_update_dpp(
             0, __float_as_int(x), 0x114, 0xf, 0xf, true));
    x += __int_as_float(__builtin_amdgcn_update_dpp(
             0, __float_as_int(x), 0x118, 0xf, 0xf, true));
    x += __int_as_float(__builtin_amdgcn_update_dpp(
             0, __float_as_int(x), 0x142, 0xf, 0xf, true));  // row_bcast:15
    return x;
}

// ---------------------------------------------------------------------------
// fused |fhat|^2 + transpose + bin-partials (unchanged).
// ---------------------------------------------------------------------------
__global__ __launch_bounds__(256)
void k_binpart(const float2* __restrict__ in, float* __restrict__ pB,
               float* __restrict__ pM) {
    __shared__ float tile[32][33];
    const int bx = blockIdx.x * 32, by = blockIdx.y * 32;
    const int tx = threadIdx.x, ty = threadIdx.y;
#pragma unroll
    for (int j = 0; j < 32; j += 8) {
        const float2 v = in[(size_t)(by + ty + j) * 1024 + bx + tx];
        tile[ty + j][tx] = v.x * v.x + v.y * v.y;
    }
    __syncthreads();
    const int sIdx = blockIdx.y;              // slab (which 32-col group)
    const float d = ((float)(by + tx) - 511.5f) * FINV_T;  // fr - bin center
    const int lane = (tx + 32 * ty) & 63;
#pragma unroll
    for (int j = 0; j < 32; j += 8) {
        float s = tile[tx][ty + j];           // m2 at (r_true=bx+ty+j, c_true=by+tx)
        float m = s * d;
        s = dpp_sum32(s);
        m = dpp_sum32(m);
        if (lane == 31 || lane == 63) {
            const int bin = bx + ty + j;      // = r_true
            pB[bin * 32 + sIdx] = s;
            pM[bin * 32 + sIdx] = m;
        }
    }
}

// ---------------------------------------------------------------------------
// 49 omega updates over 1024 bins: 256 threads x 4 bins (4 waves, 1/SIMD).
// Parked: latency-chain floor ~56.6us (rounds 12-17 bracket it).
// ---------------------------------------------------------------------------
__global__ __launch_bounds__(256)
void k_omega(const float* __restrict__ pB, const float* __restrict__ pM,
             const float* __restrict__ omega0,
             float* __restrict__ oomf, float* __restrict__ sgsb) {
    const int tid = threadIdx.x;
    const int lane = tid & 63, wid = tid >> 6;   // 4 waves
    const float kA = -4.0f * FALPHA;

    float B[4], M[4], C[4], SG[4], gp[4];
    const float4* __restrict__ pB4 = (const float4*)pB;
    const float4* __restrict__ pM4 = (const float4*)pM;
#pragma unroll
    for (int i = 0; i < 4; ++i) {
        const int j = tid + 256 * i;
        float sb = 0.f, sm = 0.f;
#pragma unroll
        for (int s = 0; s < 8; ++s) {         // fixed order -> deterministic
            const float4 b = pB4[j * 8 + s];
            sb += b.x; sb += b.y; sb += b.z; sb += b.w;
            const float4 m = pM4[j * 8 + s];
            sm += m.x; sm += m.y; sm += m.z; sm += m.w;
        }
        B[i] = sb; M[i] = sm;
        C[i] = ((float)(j * PPB) + 511.5f) * FINV_T - 0.5f;
        SG[i] = 0.f; gp[i] = 0.f;
    }

    float om0 = 0.5f * omega0[0];
    float om1 = 0.5f * omega0[1];
    float om2 = 0.5f * omega0[2];
    float op0 = om0, op1 = om1, op2 = om2;
    float n0 = om0, n1 = om1, n2 = om2;
    float stop = 0.f;

    __shared__ float wsum[2][4][8];           // parity double-buffer
    bool fin = true;

    for (int n = 0; n < 49; ++n) {
        if (n > 0) {
            if (stop != 0.f) { fin = false; break; }
            op0 = om0; op1 = om1; op2 = om2;
            om0 = n0; om1 = n1; om2 = n2;
#pragma unroll
            for (int i = 0; i < 4; ++i) SG[i] += gp[i] - 1.0f;  // gs_{n-1}
        }
        const int check = (n > 0 && n % 10 == 0);

        float a[8];
#pragma unroll
        for (int v = 0; v < 8; ++v) a[v] = 0.f;

#pragma unroll
        for (int i = 0; i < 4; ++i) {
            const float c  = C[i];
            const float Bv = B[i];
            const float M1 = M[i];
            const float e0 = c - om0, e1 = c - om1, e2 = c - om2;
            float g0, g1, g2;
            g3f(c, om0, om1, om2, g0, g1, g2);
            const float gsq0 = g0 * g0, gsq1 = g1 * g1, gsq2 = g2 * g2;
            const float gc0 = gsq0 * g0, gc1 = gsq1 * g1, gc2 = gsq2 * g2;
            const float Dp0 = e0 + e1, Dp1 = e0 + e1 + e2, Dp2 = e1 + e2;
            const float P0 = gsq0 * Bv + kA * Dp0 * gc0 * M1;
            const float P1 = gsq1 * Bv + kA * Dp1 * gc1 * M1;
            const float P2 = gsq2 * Bv + kA * Dp2 * gc2 * M1;
            a[0] += P0; a[1] += P1; a[2] += P2;
            a[3] += c * P0 + gsq0 * M1;
            a[4] += c * P1 + gsq1 * M1;
            a[5] += c * P2 + gsq2 * M1;
            gp[i] = g0 + g1 + g2;
            if (check) {
                float h0, h1, h2;
                g3f(c, op0, op1, op2, h0, h1, h2);
                const float d0 = g0 - h0, d1 = g1 - h1, d2 = g2 - h2;
                a[6] += Bv * (d0 * d0 + d1 * d1 + d2 * d2);
                a[7] += Bv * (h0 * h0 + h1 * h1 + h2 * h2);
            }
        }
#pragma unroll
        for (int v = 0; v < 6; ++v) a[v] = dpp_wave_sum(a[v]);
        if (check) {
            a[6] = dpp_wave_sum(a[6]);
            a[7] = dpp_wave_sum(a[7]);
        }
        if (lane == 63) {
            *(float4*)&wsum[n & 1][wid][0] = make_float4(a[0], a[1], a[2], a[3]);
            *(float4*)&wsum[n & 1][wid][4] = make_float4(a[4], a[5], a[6], a[7]);
        }
        __syncthreads();                       // the ONLY barrier per iter
        float r = 0.f;
#pragma unroll
        for (int w = 0; w < 4; ++w) r += wsum[n & 1][w][lane & 7];
        const float S0 = rlanef(r, 0), S1 = rlanef(r, 1), S2 = rlanef(r, 2);
        const float S3 = rlanef(r, 3), S4 = rlanef(r, 4), S5 = rlanef(r, 5);
        n0 = S3 * __builtin_amdgcn_rcpf(S0 + FEPS);
        n1 = S4 * __builtin_amdgcn_rcpf(S1 + FEPS);
        n2 = S5 * __builtin_amdgcn_rcpf(S2 + FEPS);
        if (check) {
            const float S6 = rlanef(r, 6), S7 = rlanef(r, 7);
            const float ud = S6 * __builtin_amdgcn_rcpf(S7 + FEPS);
            const float od = (fabsf(n0 - n2) + fabsf(n1 - n0) +
                              fabsf(n2 - n1)) * (1.0f / 3.0f);
            stop = (ud < FTOL && od < FTOL) ? 1.f : 0.f;
        }
    }

    if (fin) {             // completed: omega entering iter 49, sgs 0..48
#pragma unroll
        for (int i = 0; i < 4; ++i) SG[i] += gp[i] - 1.0f;
        om0 = n0; om1 = n1; om2 = n2;
    }
#pragma unroll
    for (int i = 0; i < 4; ++i) sgsb[tid + 256 * i] = SG[i];
    if (tid == 0) { oomf[0] = om0; oomf[1] = om1; oomf[2] = om2; }
}

// ---------------------------------------------------------------------------
// 1024-point Stockham radix-4 stages in LDS, PADDED indexing (PADI).
// 256-thread single-column version (row FFT kernels).
// ---------------------------------------------------------------------------
__device__ __forceinline__ float2* fft1024_stages(float2* bufA, float2* bufB,
                                                  int t, float dir) {
    float2* src = bufA;
    float2* dst = bufB;
    int Ns = 1;
#pragma unroll
    for (int s = 0; s < 5; ++s) {
        const int jm = t & (Ns - 1);
        float2 v0 = src[PADI(t)],       v1 = src[PADI(t + 256)];
        float2 v2 = src[PADI(t + 512)], v3 = src[PADI(t + 768)];
        const float rv = (float)jm * (0.25f / (float)Ns);
        float2 w1 = cis_rev(rv, dir);
        float2 w2 = cmulf(w1, w1);
        float2 w3 = cmulf(w2, w1);
        v1 = cmulf(v1, w1); v2 = cmulf(v2, w2); v3 = cmulf(v3, w3);
        float2 s0 = make_float2(v0.x + v2.x, v0.y + v2.y);
        float2 s1 = make_float2(v0.x - v2.x, v0.y - v2.y);
        float2 s2 = make_float2(v1.x + v3.x, v1.y + v3.y);
        float2 s3 = make_float2(v1.x - v3.x, v1.y - v3.y);
        float2 s3i = make_float2(-dir * s3.y, dir * s3.x);  // dir*i * s3
        const int base = ((t - jm) << 2) + jm;
        dst[PADI(base)]          = make_float2(s0.x + s2.x, s0.y + s2.y);
        dst[PADI(base + Ns)]     = make_float2(s1.x + s3i.x, s1.y + s3i.y);
        dst[PADI(base + 2 * Ns)] = make_float2(s0.x - s2.x, s0.y - s2.y);
        dst[PADI(base + 3 * Ns)] = make_float2(s1.x - s3i.x, s1.y - s3i.y);
        __syncthreads();
        float2* tmp = src; src = dst; dst = tmp;
        Ns <<= 2;
    }
    return src;
}

// 512-thread 4-column slab driver: half-block h = tid>>8 owns columns
// {2h, 2h+1}; 2 butterflies/thread/stage.  Buffers [4][PBUF].  Barriers
// sync all 8 waves.  Per-column arithmetic identical to fft1024_stages.
__device__ __forceinline__ float2* fft1024_stages2x(float2* bufA, float2* bufB,
                                                    int t, int h, float dir) {
    float2* src = bufA;
    float2* dst = bufB;
    int Ns = 1;
#pragma unroll
    for (int s = 0; s < 5; ++s) {
        const int jm = t & (Ns - 1);
        const float rv = (float)jm * (0.25f / (float)Ns);
        float2 w1 = cis_rev(rv, dir);
        float2 w2 = cmulf(w1, w1);
        float2 w3 = cmulf(w2, w1);
        const int base = ((t - jm) << 2) + jm;
#pragma unroll
        for (int qq = 0; qq < 2; ++qq) {
            const int o = (2 * h + qq) * PBUF;
            float2 v0 = src[o + PADI(t)],       v1 = src[o + PADI(t + 256)];
            float2 v2 = src[o + PADI(t + 512)], v3 = src[o + PADI(t + 768)];
            v1 = cmulf(v1, w1); v2 = cmulf(v2, w2); v3 = cmulf(v3, w3);
            float2 s0 = make_float2(v0.x + v2.x, v0.y + v2.y);
            float2 s1 = make_float2(v0.x - v2.x, v0.y - v2.y);
            float2 s2 = make_float2(v1.x + v3.x, v1.y + v3.y);
            float2 s3 = make_float2(v1.x - v3.x, v1.y - v3.y);
            float2 s3i = make_float2(-dir * s3.y, dir * s3.x);
            dst[o + PADI(base)]          = make_float2(s0.x + s2.x, s0.y + s2.y);
            dst[o + PADI(base + Ns)]     = make_float2(s1.x + s3i.x, s1.y + s3i.y);
            dst[o + PADI(base + 2 * Ns)] = make_float2(s0.x - s2.x, s0.y - s2.y);
            dst[o + PADI(base + 3 * Ns)] = make_float2(s1.x - s3i.x, s1.y - s3i.y);
        }
        __syncthreads();
        float2* tmp = src; src = dst; dst = tmp;
        Ns <<= 2;
    }
    return src;
}

// generic row FFT (forward second stage), 256 threads, 4 blk/CU.
__global__ __launch_bounds__(256)
void k_fft1024(const float2* __restrict__ in, float2* __restrict__ out,
               float dir) {
    __shared__ float2 bufA[PBUF];
    __shared__ float2 bufB[PBUF];
    const int row  = blockIdx.x;
    const float2* __restrict__ rin  = in  + (size_t)row * 1024;
    float2* __restrict__ rout = out + (size_t)row * 1024;
    const int t = threadIdx.x;
#pragma unroll
    for (int r = 0; r < 4; ++r) {
        const int c = t + 256 * r;
        bufA[PADI(c)] = rin[c];
    }
    __syncthreads();
    float2* src = fft1024_stages(bufA, bufB, t, dir);
#pragma unroll
    for (int r = 0; r < 4; ++r) {
        const int c = t + 256 * r;
        rout[c] = src[PADI(c)];
    }
}

// ---------------------------------------------------------------------------
// forward slab, 512 threads: tr_fwd_in + fft1024(tw) + tr_c2c in one pass.
// ---------------------------------------------------------------------------
__global__ __launch_bounds__(512)
void k_fftfwd_slab(const float* __restrict__ x, float2* __restrict__ sA) {
    __shared__ float2 bufA[4][PBUF];
    __shared__ float2 bufB[4][PBUF];
    const int a0  = blockIdx.x * 4;
    const int tid = threadIdx.x;
    const int t = tid & 255, h = tid >> 8;
#pragma unroll
    for (int r = 0; r < 2; ++r) {
        const int p = tid + 512 * r;
        const float4 v = *(const float4*)(x + (size_t)p * 1024 + a0);
        const int pi = PADI(p);
        bufA[0][pi] = make_float2( v.x, 0.f);
        bufA[1][pi] = make_float2(-v.y, 0.f);
        bufA[2][pi] = make_float2( v.z, 0.f);
        bufA[3][pi] = make_float2(-v.w, 0.f);
    }
    __syncthreads();
    float2* src = fft1024_stages2x(&bufA[0][0], &bufB[0][0], t, h, -1.0f);
#pragma unroll
    for (int r = 0; r < 2; ++r) {
        const int c = tid + 512 * r;
        const int ci = PADI(c);
        float2 o[4];
#pragma unroll
        for (int q = 0; q < 4; ++q) {
            const unsigned p = ((unsigned)(a0 + q) * (unsigned)c) & 1048575u;
            o[q] = cmulf(src[q * PBUF + ci], cis_rev((float)p * FINV_T, -1.0f));
        }
        float2* w = sA + (size_t)c * 1024 + a0;
        *(float4*)(w)     = make_float4(o[0].x, o[0].y, o[1].x, o[1].y);
        *(float4*)(w + 2) = make_float4(o[2].x, o[2].y, o[3].x, o[3].y);
    }
}

// ---------------------------------------------------------------------------
// inverse slab, 512 threads: tr_c2c + fft1024(inv) + tr_out in one pass.
// ---------------------------------------------------------------------------
__global__ __launch_bounds__(512)
void k_ifft_slab(const float2* __restrict__ zin, float* __restrict__ out,
                 int zbase) {
    __shared__ float2 bufA[4][PBUF];
    __shared__ float2 bufB[4][PBUF];
    const int m0  = blockIdx.x * 4;
    const int zi  = blockIdx.y;
    const int z   = zi + zbase;
    const int tid = threadIdx.x;
    const int t = tid & 255, h = tid >> 8;
    const float2* __restrict__ Z = zin + (size_t)zi * TN;
#pragma unroll
    for (int r = 0; r < 2; ++r) {
        const int k = tid + 512 * r;
        const float4 u0 = *(const float4*)(Z + (size_t)k * 1024 + m0);
        const float4 u1 = *(const float4*)(Z + (size_t)k * 1024 + m0 + 2);
        const int ki = PADI(k);
        bufA[0][ki] = make_float2(u0.x, u0.y);
        bufA[1][ki] = make_float2(u0.z, u0.w);
        bufA[2][ki] = make_float2(u1.x, u1.y);
        bufA[3][ki] = make_float2(u1.z, u1.w);
    }
    __syncthreads();
    float2* src = fft1024_stages2x(&bufA[0][0], &bufB[0][0], t, h, 1.0f);
#pragma unroll
    for (int r = 0; r < 2; ++r) {
        const int m2 = tid + 512 * r;
        const int mi = PADI(m2);
        float re[4], im[4];
#pragma unroll
        for (int q = 0; q < 4; ++q) {
            const float sgn = (q & 1) ? -FINV_T : FINV_T;   // (-1)^{m0+q}, m0 even
            const float2 v = src[q * PBUF + mi];
            re[q] = v.x * sgn;
            im[q] = v.y * sgn;
        }
        const size_t idx = (size_t)m2 * 1024 + m0;
        if (z == 0) {
            *(float4*)(out + idx) =
                make_float4(re[0], re[1], re[2], re[3]);            // imf0
            *(float4*)(out + (size_t)TN + idx) =
                make_float4(im[0], im[1], im[2], im[3]);            // imf1
        } else {
            *(float4*)(out + 2 * (size_t)TN + idx) =
                make_float4(re[0], re[1], re[2], re[3]);            // imf2
        }
    }
}

// single-z filter + row-iFFT (non-batch2 workspace path), 256 threads.
__global__ __launch_bounds__(256)
void k_fftu(const float2* __restrict__ fhat, const float* __restrict__ sgsb,
            const float* __restrict__ oomf,
            float2* __restrict__ out, int zbase) {
    __shared__ float2 bufA[PBUF];
    __shared__ float2 bufB[PBUF];
    const int row = blockIdx.x & 1023;
    const int zi  = blockIdx.x >> 10;
    const int z   = zi + zbase;
    const float om0 = oomf[0], om1 = oomf[1], om2 = oomf[2];
    const float2* __restrict__ frow = fhat + (size_t)row * 1024;
    const int t = threadIdx.x;
#pragma unroll
    for (int r = 0; r < 4; ++r) {
        const int c = t + 256 * r;
        const float2 f = frow[c];
        const int tt = (c << 10) | row;
        const float fr = (float)tt * FINV_T - 0.5f;
        const float sc = 1.0f - 0.5f * FTAU * sgsb[tt >> 10];
        float g0, g1, g2;
        g3f(fr, om0, om1, om2, g0, g1, g2);
        const int tm = (TN - tt) & (TN - 1);
        const float frm = (float)tm * FINV_T - 0.5f;
        const float scm = 1.0f - 0.5f * FTAU * sgsb[tm >> 10];
        float h0, h1, h2;
        g3f(frm, om0, om1, om2, h0, h1, h2);
        float A, Bi;
        if (z == 0) {
            A  = 0.5f * (g0 * sc + h0 * scm);
            Bi = 0.5f * (g1 * sc + h1 * scm);
        } else {
            A  = 0.5f * (g2 * sc + h2 * scm);
            Bi = 0.f;
        }
        bufA[PADI(c)] = cmulf(f, make_float2(A, Bi));
    }
    __syncthreads();
    float2* src = fft1024_stages(bufA, bufB, t, 1.0f);
    float2* __restrict__ rout = out + (size_t)zi * TN + (size_t)row * 1024;
#pragma unroll
    for (int r = 0; r < 4; ++r) {
        const int c = t + 256 * r;
        const unsigned p = ((unsigned)row * (unsigned)c) & 1048575u;
        rout[c] = cmulf(src[PADI(c)], cis_rev((float)p * FINV_T, 1.0f));
    }
}

// fused both-z variant, 512 threads: one fhat load + one g3f set fills BOTH
// filter buffers; the two 1024-pt iFFTs then run CONCURRENTLY (h=0 group on
// z0 buffers, h=1 on z1).  Same per-element ops/order as the serial version.
__global__ __launch_bounds__(512)
void k_fftu2(const float2* __restrict__ fhat, const float* __restrict__ sgsb,
             const float* __restrict__ oomf, float2* __restrict__ out) {
    __shared__ float2 b0A[PBUF], b0B[PBUF];
    __shared__ float2 b1A[PBUF], b1B[PBUF];
    const int row = blockIdx.x;
    const float om0 = oomf[0], om1 = oomf[1], om2 = oomf[2];
    const float2* __restrict__ frow = fhat + (size_t)row * 1024;
    const int tid = threadIdx.x;
    const int t = tid & 255, h = tid >> 8;
#pragma unroll
    for (int e = 0; e < 2; ++e) {
        const int c = tid + 512 * e;
        const float2 f = frow[c];
        const int tt = (c << 10) | row;
        const float fr = (float)tt * FINV_T - 0.5f;
        const float sc = 1.0f - 0.5f * FTAU * sgsb[tt >> 10];
        float g0, g1, g2;
        g3f(fr, om0, om1, om2, g0, g1, g2);
        const int tm = (TN - tt) & (TN - 1);
        const float frm = (float)tm * FINV_T - 0.5f;
        const float scm = 1.0f - 0.5f * FTAU * sgsb[tm >> 10];
        float h0, h1, h2;
        g3f(frm, om0, om1, om2, h0, h1, h2);
        const float A  = 0.5f * (g0 * sc + h0 * scm);
        const float Bi = 0.5f * (g1 * sc + h1 * scm);
        const float A2 = 0.5f * (g2 * sc + h2 * scm);
        const int ci = PADI(c);
        b0A[ci] = cmulf(f, make_float2(A, Bi));
        b1A[ci] = make_float2(f.x * A2, f.y * A2);   // = cmulf(f, (A2, 0))
    }
    __syncthreads();
    float2* bufA = h ? b1A : b0A;               // wave-uniform select
    float2* bufB = h ? b1B : b0B;
    float2* src = fft1024_stages(bufA, bufB, t, 1.0f);
    float2* __restrict__ rout = out + (size_t)h * TN + (size_t)row * 1024;
#pragma unroll
    for (int r = 0; r < 4; ++r) {
        const int c = t + 256 * r;
        const unsigned p = ((unsigned)row * (unsigned)c) & 1048575u;
        rout[c] = cmulf(src[PADI(c)], cis_rev((float)p * FINV_T, 1.0f));
    }
}

// ---------------------------------------------------------------------------
extern "C" void kernel_launch(void* const* d_in, const int* in_sizes, int n_in,
                              void* d_out, int out_size, void* d_ws, size_t ws_size,
                              hipStream_t stream) {
    (void)in_sizes; (void)n_in; (void)out_size;
    const float* x      = (const float*)d_in[0];
    const float* omega0 = (const float*)d_in[1];
    float* outp = (float*)d_out;
    char* ws = (char*)d_ws;

    const size_t MB = (size_t)1 << 20;
    const size_t KB = (size_t)1 << 10;
    float2* fhat = (float2*)(ws);                      // 8 MB (scrambled)
    float*  pB   = (float*)(ws + 8 * MB);              // 128 KB
    float*  pM   = (float*)(ws + 8 * MB + 128 * KB);   // 128 KB
    float*  sgsb = (float*)(ws + 8 * MB + 256 * KB);   // 4 KB
    float*  oomf = (float*)(ws + 8 * MB + 264 * KB);   // 3 floats
    const bool batch2 = ws_size >= 42 * MB;
    float2* sA = (float2*)(ws + 9 * MB);               // 8 MB
    float2* sB = batch2 ? (float2*)(ws + 25 * MB)      // 16 MB (both z)
                        : (float2*)(ws + 17 * MB);     // 8 MB (one z)

    // forward: slab col-FFT (+twiddle, transposed write) then row FFT
    k_fftfwd_slab<<<256, 512, 0, stream>>>(x, sA);
    k_fft1024<<<1024, 256, 0, stream>>>(sA, fhat, -1.0f);

    // fused spectrum compression: fhat -> per-slab bin partials
    k_binpart<<<dim3(32, 32), dim3(32, 8), 0, stream>>>(fhat, pB, pM);

    // 49 omega updates in one small block
    k_omega<<<1, 256, 0, stream>>>(pB, pM, omega0, oomf, sgsb);

    // Hermitian-packed inverse: filter + both row-iFFTs concurrently, then
    // slab col-iFFT writing the 3 real IMFs in natural order.
    if (batch2) {
        k_fftu2<<<1024, 512, 0, stream>>>(fhat, sgsb, oomf, sB);
        k_ifft_slab<<<dim3(256, 2), 512, 0, stream>>>(sB, outp, 0);
    } else {
        for (int z = 0; z < 2; ++z) {
            k_fftu<<<1024, 256, 0, stream>>>(fhat, sgsb, oomf, sB, z);
            k_ifft_slab<<<dim3(256, 1), 512, 0, stream>>>(sB, outp, z);
        }
    }
}